// Round 7
// baseline (2881.386 us; speedup 1.0000x reference)
//
#include <hip/hip_runtime.h>

// 5-layer stacked LSTM, T=512 B=256 IN=64 H=128. Storage fp32; internal bf16
// MFMA with fp32 accum (R3 verified, absmax 4.9e-4).
//
// R12: MEASUREMENT ROUND. Real kernel = R11 verbatim (verified). Appended two
// self-contained ablation dispatches (no cross-block waits, flag writes to
// scratch ints) that mimic the KIN=128 body exactly:
//   abl_body<true,768>   full local body        -> local steady rate
//   abl_body<false,1280> gates stubbed (2 ops)  -> body minus gate/trans
// Readout: top-5 is duration-sorted. A visible => body-internal bottleneck;
// A absent => >=600cy coupling. rate(A)-rate(B) = gate share. dur_us is
// sacrificed this round (~3ms) for the decomposition.
//
// R10/R11 recap: grouped (4-body) fetch/commit, head-only vmcnt drains, LDS
// flag mirrors, 8-deep LDS x-ring, contiguous 4KB ring tiles, relaxed agent
// atomics, lgkm-only body barriers, 96KB LDS occupancy fence (1 block/CU).
// Fallback: R3 layer-sequential path if ws too small.

typedef unsigned short ushort_t;
typedef unsigned int uint_t;
typedef unsigned long long ull_t;
typedef __attribute__((ext_vector_type(8))) short short8;
typedef __attribute__((ext_vector_type(4))) float floatx4;
typedef __attribute__((ext_vector_type(2))) float floatx2;

#define T_STEPS 512
#define BATCH   256
#define HID     128
#define NL      5
#define NBG     16
#define RING_R  64
#define PRIME   24
#define FLAG_STRIDE 16
#define SLOT_U  (BATCH * HID / 2)                  // uints per ring slot
#define RING_U  ((size_t)RING_R * SLOT_U)          // uints per layer ring
#define WS_NEED (8192 + 4 * RING_U * 4)
#define LDS_BYTES 98304   // 96KB occupancy fence (carve uses ~43.5KB)

__device__ __forceinline__ ushort_t f2bf(float f) {
  unsigned int u = __float_as_uint(f);
  u += 0x7FFF + ((u >> 16) & 1);  // RNE; values here are finite
  return (ushort_t)(u >> 16);
}
__device__ __forceinline__ float sigm(float x) {
  float e = __builtin_amdgcn_exp2f(-1.442695041f * x);
  return __builtin_amdgcn_rcpf(1.0f + e);
}
__device__ __forceinline__ float tanh_(float x) {
  float e = __builtin_amdgcn_exp2f(-2.885390082f * x);
  float s = __builtin_amdgcn_rcpf(1.0f + e);
  return __builtin_fmaf(2.0f, s, -1.0f);
}
__device__ __forceinline__ int flag_ld(const int* p) {
  return __hip_atomic_load(p, __ATOMIC_RELAXED, __HIP_MEMORY_SCOPE_AGENT);
}
__device__ __forceinline__ ull_t ring_ld8(const uint_t* base, int tid) {
  return __hip_atomic_load((const ull_t*)base + tid, __ATOMIC_RELAXED,
                           __HIP_MEMORY_SCOPE_AGENT);
}
__device__ __forceinline__ void ring_st8(uint_t* base, int tid, ull_t v) {
  __hip_atomic_store((ull_t*)base + tid, v, __ATOMIC_RELAXED,
                     __HIP_MEMORY_SCOPE_AGENT);
}

__global__ void init_flags(int* flags) {
  int i = blockIdx.x * 256 + threadIdx.x;
  if (i < NL * NBG * FLAG_STRIDE)
    __hip_atomic_store(&flags[i], 0, __ATOMIC_RELAXED,
                       __HIP_MEMORY_SCOPE_AGENT);
}

// ---------------------------------------------------------------- pipeline --
template <int KIN, bool SRC_F32, bool RING_OUT>
__device__ __forceinline__ void lstm_stage(
    unsigned char* lds,
    const float* xf32,              // layer-0 input (fp32) if SRC_F32
    const uint_t* ring_in,          // upstream ring (bf16 tiles)
    const float* __restrict__ Wih, const float* __restrict__ Whh,
    const float* __restrict__ bih, const float* __restrict__ bhh,
    uint_t* ring_out,               // this layer's ring (RING_OUT)
    float* out_f32,                 // d_out (last layer only)
    int* up_flag, int* down_flag, int* my_flag, int bg)
{
  constexpr int KX = KIN / 32, KT = KX + 4;
  constexpr int XS = KIN + 8;      // padded x row (ushorts)
  constexpr int HS = 128 + 8;

  typedef ushort_t (*XT)[16][XS];
  typedef ushort_t (*HT)[16][HS];
  XT Xr = (XT)lds;                                         // [8][16][XS]
  HT Hr = (HT)(lds + (size_t)8 * 16 * XS * 2);             // [2][16][HS]
  int* upm = (int*)(lds + (size_t)8 * 16 * XS * 2 + (size_t)2 * 16 * HS * 2);
  int* dnm = upm + 4;

  const int tid  = threadIdx.x;
  const int wave = tid >> 6;
  const int lane = tid & 63;
  const int col  = lane & 15;        // MFMA: A row / D col
  const int quad = lane >> 4;        // MFMA: k-group / D row-group
  const int j    = wave * 16 + col;  // gate/h column owned by this lane
  const int frow = tid >> 5;         // staging row (16)
  const int fc   = tid & 31;         // staging col group (32)

  for (int i = tid; i < 2 * 16 * HS; i += 512) (&Hr[0][0][0])[i] = 0;
  if (tid == 0) {
#pragma unroll
    for (int i = 0; i < 4; ++i) { upm[i] = 0; dnm[i] = 0; }  // under-report ok
  }

  // Wcat^T fragments, fp32 -> bf16 once, VGPR-resident all 512 steps.
  short8 wf[4][KT];
#pragma unroll
  for (int nt = 0; nt < 4; ++nt) {
    int n = nt * 128 + j;
#pragma unroll
    for (int kt = 0; kt < KX; ++kt) {
      const float* p = Wih + n * KIN + kt * 32 + quad * 8;
      short8 w;
#pragma unroll
      for (int e = 0; e < 8; ++e) w[e] = (short)f2bf(p[e]);
      wf[nt][kt] = w;
    }
#pragma unroll
    for (int kt = 0; kt < 4; ++kt) {
      const float* p = Whh + n * 128 + kt * 32 + quad * 8;
      short8 w;
#pragma unroll
      for (int e = 0; e < 8; ++e) w[e] = (short)f2bf(p[e]);
      wf[nt][KX + kt] = w;
    }
  }
  const float bi  = bih[j]       + bhh[j];
  const float bf_ = bih[128 + j] + bhh[128 + j];
  const float bgi = bih[256 + j] + bhh[256 + j];
  const float bo  = bih[384 + j] + bhh[384 + j];

  floatx4 c = {0.f, 0.f, 0.f, 0.f};
  int pu = 0, pd = 0;           // tid0 pending flag loads
  ull_t  pf4[4];                // in-flight group fetch (ring path)
  floatx2 px4[4];               // in-flight group fetch (layer-0 path)

  __syncthreads();  // zero-init + mirror init visible

  // ---------------- prologue: lag priming + commit slots 0..7 -------------
  if constexpr (!SRC_F32) {
    int v = 0;
    while ((v = flag_ld(up_flag)) < PRIME) __builtin_amdgcn_s_sleep(1);
    asm volatile("" ::: "memory");
    if (tid == 0) {
#pragma unroll
      for (int i = 0; i < 4; ++i) upm[i] = v;
      pu = v;
    }
    ull_t pr[8];
#pragma unroll
    for (int s = 0; s < 8; ++s)
      pr[s] = ring_ld8(ring_in + (size_t)s * SLOT_U + bg * 1024, tid);
#pragma unroll
    for (int s = 0; s < 8; ++s)
      *(ull_t*)(&Xr[s][frow][fc * 4]) = pr[s];
  } else {
    floatx2 pr[8];
#pragma unroll
    for (int s = 0; s < 8; ++s)
      pr[s] = *(const floatx2*)(xf32 +
                                ((size_t)s * BATCH + bg * 16 + frow) * 64 +
                                fc * 2);
#pragma unroll
    for (int s = 0; s < 8; ++s)
      *(uint_t*)(&Xr[s][frow][fc * 2]) =
          (uint_t)f2bf(pr[s][0]) | ((uint_t)f2bf(pr[s][1]) << 16);
  }
  // NO pre-issue here (R9 bug): head 0 issues slots 8..11.
  asm volatile("s_waitcnt lgkmcnt(0)\n\ts_barrier" ::: "memory");

  for (int t = 0; t < T_STEPS; ++t) {
    if ((t & 3) == 0) {
      if (t >= 4) {
        // ---- head drain: publishes AND lands the 4 prefetch loads ----
        asm volatile("s_waitcnt vmcnt(0)\n\ts_barrier" ::: "memory");
        if (tid == 0)
          __hip_atomic_store(my_flag, t - 1, __ATOMIC_RELAXED,
                             __HIP_MEMORY_SCOPE_AGENT);
        // ---- commit slots t+4..t+7 (pos half disjoint from reads) ----
#pragma unroll
        for (int g = 0; g < 4; ++g) {
          const int s = t + 4 + g;
          if (s < T_STEPS) {
            if constexpr (SRC_F32)
              *(uint_t*)(&Xr[s & 7][frow][fc * 2]) =
                  (uint_t)f2bf(px4[g][0]) | ((uint_t)f2bf(px4[g][1]) << 16);
            else
              *(ull_t*)(&Xr[s & 7][frow][fc * 4]) = pf4[g];
          }
        }
      }
      // ---- issue fetch of slots t+8..t+11 (commit at head t+4) ----
      if (t + 8 < T_STEPS) {
        if constexpr (!SRC_F32) {
          int need = t + 12;
          if (need > T_STEPS) need = T_STEPS;
          if (upm[t & 3] < need) {               // steady state: never
            while (flag_ld(up_flag) < need) __builtin_amdgcn_s_sleep(1);
          }
        }
        asm volatile("" ::: "memory");  // no load hoisting above the gate
#pragma unroll
        for (int g = 0; g < 4; ++g) {
          const int s = t + 8 + g;
          if (s < T_STEPS) {
            if constexpr (SRC_F32)
              px4[g] = *(const floatx2*)(
                  xf32 + ((size_t)s * BATCH + bg * 16 + frow) * 64 + fc * 2);
            else
              pf4[g] = ring_ld8(
                  ring_in + (size_t)(s & (RING_R - 1)) * SLOT_U + bg * 1024,
                  tid);
          }
        }
      }
    }
    const int dn = dnm[t & 3];   // broadcast LDS read (written body t-2)

    // ---- export h_{t-1} (contiguous 4KB tile, fire-and-forget) ----
    if constexpr (RING_OUT) {
      if (t >= 1) {
        const int s = t - 1;
        if (s - dn > RING_R - 16) {                    // rare: direct spin
          while (s - flag_ld(down_flag) > RING_R - 16)
            __builtin_amdgcn_s_sleep(1);
          asm volatile("" ::: "memory");
        }
        ull_t h8 = *(const ull_t*)(&Hr[t & 1][frow][fc * 4]);
        ring_st8(ring_out + (size_t)(s & (RING_R - 1)) * SLOT_U + bg * 1024,
                 tid, h8);
      }
    }

    // ---- A fragments + MFMA ----
    short8 af[KT];
#pragma unroll
    for (int kt = 0; kt < KX; ++kt)
      af[kt] = *(const short8*)(&Xr[t & 7][col][kt * 32 + quad * 8]);
#pragma unroll
    for (int kt = 0; kt < 4; ++kt)
      af[KX + kt] = *(const short8*)(&Hr[t & 1][col][kt * 32 + quad * 8]);
    floatx4 a0 = {0, 0, 0, 0}, a1 = {0, 0, 0, 0}, a2 = {0, 0, 0, 0},
            a3 = {0, 0, 0, 0};
#pragma unroll
    for (int kt = 0; kt < KT; ++kt) {
      short8 a = af[kt];
      a0 = __builtin_amdgcn_mfma_f32_16x16x32_bf16(a, wf[0][kt], a0, 0, 0, 0);
      a1 = __builtin_amdgcn_mfma_f32_16x16x32_bf16(a, wf[1][kt], a1, 0, 0, 0);
      a2 = __builtin_amdgcn_mfma_f32_16x16x32_bf16(a, wf[2][kt], a2, 0, 0, 0);
      a3 = __builtin_amdgcn_mfma_f32_16x16x32_bf16(a, wf[3][kt], a3, 0, 0, 0);
    }

    // ---- tid0 flag-mirror maintenance (commit old, issue new) ----
    if (tid == 0) {
      if constexpr (!SRC_F32) {
        upm[(t + 2) & 3] = pu;
        pu = flag_ld(up_flag);
      }
      if constexpr (RING_OUT) {
        dnm[(t + 2) & 3] = pd;
        pd = flag_ld(down_flag);
      }
    }

    // ---- cell update (lane-local) ----
    ushort_t (*wr)[HS] = Hr[(t & 1) ^ 1];
#pragma unroll
    for (int r = 0; r < 4; ++r) {
      float iv = sigm(a0[r] + bi);
      float fv = sigm(a1[r] + bf_);
      float gv = tanh_(a2[r] + bgi);
      float ov = sigm(a3[r] + bo);
      float cn = __builtin_fmaf(fv, c[r], iv * gv);
      c[r] = cn;
      float hv = ov * tanh_(cn);
      wr[quad * 4 + r][j] = f2bf(hv);  // own recurrence (+ export next body)
      if constexpr (!RING_OUT) {
        out_f32[((size_t)t * BATCH + bg * 16 + quad * 4 + r) * HID + j] = hv;
      }
    }

    // LDS-only barrier: orders buffers; agent stores stay in flight
    asm volatile("s_waitcnt lgkmcnt(0)\n\ts_barrier" ::: "memory");
  }

  // ---- epilogue: export h_{T-1}, drain, final publish ----
  if constexpr (RING_OUT) {
    const int s = T_STEPS - 1;
    while (s - flag_ld(down_flag) > RING_R - 16) __builtin_amdgcn_s_sleep(1);
    asm volatile("" ::: "memory");
    ull_t h8 = *(const ull_t*)(&Hr[T_STEPS & 1][frow][fc * 4]);
    ring_st8(ring_out + (size_t)(s & (RING_R - 1)) * SLOT_U + bg * 1024, tid,
             h8);
  }
  asm volatile("s_waitcnt vmcnt(0)\n\ts_barrier" ::: "memory");
  if (tid == 0)
    __hip_atomic_store(my_flag, T_STEPS, __ATOMIC_RELAXED,
                       __HIP_MEMORY_SCOPE_AGENT);
}

__global__ __launch_bounds__(512) void lstm_pipe(
    const float* x, const float* Wih0, const float* WihR,
    const float* Whh, const float* bih, const float* bhh,
    float* out, uint_t* ring, int* flags)
{
  __shared__ __align__(16) unsigned char lds_raw[LDS_BYTES];
  const int l  = blockIdx.x >> 4;   // blockIdx = l*16+bg -> bg%8 XCD affinity
  const int bg = blockIdx.x & 15;
  int* mine = flags + (l * NBG + bg) * FLAG_STRIDE;
  int* up   = (l > 0) ? flags + ((l - 1) * NBG + bg) * FLAG_STRIDE : nullptr;
  int* down = (l < 4) ? flags + ((l + 1) * NBG + bg) * FLAG_STRIDE : nullptr;

  if (l == 0) {
    lstm_stage<64, true, true>(lds_raw, x, nullptr, Wih0, Whh, bih, bhh,
                               ring, nullptr, up, down, mine, bg);
  } else if (l < 4) {
    lstm_stage<128, false, true>(lds_raw, nullptr,
                                 ring + (size_t)(l - 1) * RING_U,
                                 WihR + (size_t)(l - 1) * 512 * 128,
                                 Whh + (size_t)l * 512 * 128,
                                 bih + l * 512, bhh + l * 512,
                                 ring + (size_t)l * RING_U, nullptr,
                                 up, down, mine, bg);
  } else {
    lstm_stage<128, false, false>(lds_raw, nullptr,
                                  ring + (size_t)3 * RING_U,
                                  WihR + (size_t)3 * 512 * 128,
                                  Whh + (size_t)4 * 512 * 128,
                                  bih + 4 * 512, bhh + 4 * 512,
                                  nullptr, out, up, nullptr, mine, bg);
  }
}

// ------------------------------------------------ ablation µbench (R12) ----
// Mimics the KIN=128 RING body with ZERO cross-block waiting. Flags written
// to unused scratch ints (1280..2047 of the 8KB flag region). Ring data is
// stale real output (finite); safe to read/clobber: every replay re-inits
// flags and producers rewrite slots before consumers read them.
template <bool GATES, int ITERS>
__global__ __launch_bounds__(512) void abl_body(
    const float* __restrict__ WihR, const float* __restrict__ Whh,
    const float* __restrict__ bih, const float* __restrict__ bhh,
    uint_t* ring, int* flags)
{
  __shared__ __align__(16) unsigned char lds_raw[LDS_BYTES];
  constexpr int KIN = 128, KX = 4, KT = 8;
  constexpr int XS = KIN + 8, HS = 128 + 8;
  typedef ushort_t (*XT)[16][XS];
  typedef ushort_t (*HT)[16][HS];
  XT Xr = (XT)lds_raw;
  HT Hr = (HT)(lds_raw + (size_t)8 * 16 * XS * 2);
  int* upm = (int*)(lds_raw + (size_t)8 * 16 * XS * 2 + (size_t)2 * 16 * HS * 2);
  int* dnm = upm + 4;

  const int bg = blockIdx.x & 15;
  const int ri = (blockIdx.x >> 4) & 3;
  const uint_t* ring_in = ring + (size_t)ri * RING_U;
  uint_t* ring_out = ring + (size_t)((ri + 1) & 3) * RING_U;
  int* up_flag   = flags + (2 * NBG + bg) * FLAG_STRIDE;  // read-only here
  int* down_flag = flags + (3 * NBG + bg) * FLAG_STRIDE;
  int* scr_flag  = flags + 1280 + blockIdx.x;             // scratch publish

  const int tid  = threadIdx.x;
  const int wave = tid >> 6;
  const int lane = tid & 63;
  const int col  = lane & 15;
  const int quad = lane >> 4;
  const int j    = wave * 16 + col;
  const int frow = tid >> 5;
  const int fc   = tid & 31;

  for (int i = tid; i < 2 * 16 * HS; i += 512) (&Hr[0][0][0])[i] = 0;
  if (tid == 0) {
#pragma unroll
    for (int i = 0; i < 4; ++i) { upm[i] = 0; dnm[i] = 0; }
  }

  const float* Wih = WihR + (size_t)1 * 512 * 128;  // layer-2 weights
  const float* Whh2 = Whh + (size_t)2 * 512 * 128;
  short8 wf[4][KT];
#pragma unroll
  for (int nt = 0; nt < 4; ++nt) {
    int n = nt * 128 + j;
#pragma unroll
    for (int kt = 0; kt < KX; ++kt) {
      const float* p = Wih + n * KIN + kt * 32 + quad * 8;
      short8 w;
#pragma unroll
      for (int e = 0; e < 8; ++e) w[e] = (short)f2bf(p[e]);
      wf[nt][kt] = w;
    }
#pragma unroll
    for (int kt = 0; kt < 4; ++kt) {
      const float* p = Whh2 + n * 128 + kt * 32 + quad * 8;
      short8 w;
#pragma unroll
      for (int e = 0; e < 8; ++e) w[e] = (short)f2bf(p[e]);
      wf[nt][KX + kt] = w;
    }
  }
  const float bi  = bih[1024 + j]       + bhh[1024 + j];
  const float bf_ = bih[1024 + 128 + j] + bhh[1024 + 128 + j];
  const float bgi = bih[1024 + 256 + j] + bhh[1024 + 256 + j];
  const float bo  = bih[1024 + 384 + j] + bhh[1024 + 384 + j];

  floatx4 c = {0.f, 0.f, 0.f, 0.f};
  int pu = 0, pd = 0;
  ull_t pf4[4];

  __syncthreads();

  // prologue: commit slots 0..7 (no waiting)
  ull_t pr[8];
#pragma unroll
  for (int s = 0; s < 8; ++s)
    pr[s] = ring_ld8(ring_in + (size_t)s * SLOT_U + bg * 1024, tid);
#pragma unroll
  for (int s = 0; s < 8; ++s)
    *(ull_t*)(&Xr[s][frow][fc * 4]) = pr[s];
  asm volatile("s_waitcnt lgkmcnt(0)\n\ts_barrier" ::: "memory");

  for (int t = 0; t < ITERS; ++t) {
    if ((t & 3) == 0) {
      if (t >= 4) {
        asm volatile("s_waitcnt vmcnt(0)\n\ts_barrier" ::: "memory");
        if (tid == 0)
          __hip_atomic_store(scr_flag, t - 1, __ATOMIC_RELAXED,
                             __HIP_MEMORY_SCOPE_AGENT);
#pragma unroll
        for (int g = 0; g < 4; ++g) {
          const int s = t + 4 + g;
          if (s < ITERS) *(ull_t*)(&Xr[s & 7][frow][fc * 4]) = pf4[g];
        }
      }
      if (t + 8 < ITERS) {
#pragma unroll
        for (int g = 0; g < 4; ++g) {
          const int s = t + 8 + g;
          if (s < ITERS)
            pf4[g] = ring_ld8(
                ring_in + (size_t)(s & (RING_R - 1)) * SLOT_U + bg * 1024,
                tid);
        }
      }
    }
    const int am = upm[t & 3];
    const int dn = dnm[t & 3];
    asm volatile("" :: "v"(am), "v"(dn));  // keep mirror reads (no DCE)

    // export (always; no guard spin)
    if (t >= 1) {
      ull_t h8 = *(const ull_t*)(&Hr[t & 1][frow][fc * 4]);
      ring_st8(ring_out + (size_t)((t - 1) & (RING_R - 1)) * SLOT_U +
                   bg * 1024,
               tid, h8);
    }

    short8 af[KT];
#pragma unroll
    for (int kt = 0; kt < KX; ++kt)
      af[kt] = *(const short8*)(&Xr[t & 7][col][kt * 32 + quad * 8]);
#pragma unroll
    for (int kt = 0; kt < 4; ++kt)
      af[KX + kt] = *(const short8*)(&Hr[t & 1][col][kt * 32 + quad * 8]);
    floatx4 a0 = {0, 0, 0, 0}, a1 = {0, 0, 0, 0}, a2 = {0, 0, 0, 0},
            a3 = {0, 0, 0, 0};
#pragma unroll
    for (int kt = 0; kt < KT; ++kt) {
      short8 a = af[kt];
      a0 = __builtin_amdgcn_mfma_f32_16x16x32_bf16(a, wf[0][kt], a0, 0, 0, 0);
      a1 = __builtin_amdgcn_mfma_f32_16x16x32_bf16(a, wf[1][kt], a1, 0, 0, 0);
      a2 = __builtin_amdgcn_mfma_f32_16x16x32_bf16(a, wf[2][kt], a2, 0, 0, 0);
      a3 = __builtin_amdgcn_mfma_f32_16x16x32_bf16(a, wf[3][kt], a3, 0, 0, 0);
    }

    if (tid == 0) {  // keep the agent flag loads (cost mimic; values unused)
      upm[(t + 2) & 3] = pu;
      pu = flag_ld(up_flag);
      dnm[(t + 2) & 3] = pd;
      pd = flag_ld(down_flag);
    }

    ushort_t (*wr)[HS] = Hr[(t & 1) ^ 1];
#pragma unroll
    for (int r = 0; r < 4; ++r) {
      if constexpr (GATES) {
        float iv = sigm(a0[r] + bi);
        float fv = sigm(a1[r] + bf_);
        float gv = tanh_(a2[r] + bgi);
        float ov = sigm(a3[r] + bo);
        float cn = __builtin_fmaf(fv, c[r], iv * gv);
        c[r] = cn;
        float hv = ov * tanh_(cn);
        wr[quad * 4 + r][j] = f2bf(hv);
      } else {
        float hv = __builtin_fmaf(a0[r], 1e-4f, c[r]);
        c[r] = hv * 0.5f;
        wr[quad * 4 + r][j] = f2bf(hv);
        asm volatile("" :: "v"(a1[r]), "v"(a2[r]), "v"(a3[r]));  // keep MFMAs
      }
    }

    asm volatile("s_waitcnt lgkmcnt(0)\n\ts_barrier" ::: "memory");
  }
  asm volatile("s_waitcnt vmcnt(0)" ::: "memory");
  if (tid == 0)
    __hip_atomic_store(scr_flag, ITERS, __ATOMIC_RELAXED,
                       __HIP_MEMORY_SCOPE_AGENT);
}

// ------------------------------------------------- fallback (R3, verified) --
template <int KIN>
__global__ __launch_bounds__(512) void lstm_layer(
    const float* xin, float* hout,
    const float* __restrict__ Wih, const float* __restrict__ Whh,
    const float* __restrict__ bih, const float* __restrict__ bhh)
{
  constexpr int KX = KIN / 32, KT = KX + 4;
  constexpr int AW = KIN + 128, AS = AW + 8;
  constexpr int NSTG = 16 * KIN / 4;

  const int bg = blockIdx.x, tid = threadIdx.x;
  const int wave = tid >> 6, lane = tid & 63;
  const int col = lane & 15, quad = lane >> 4;
  const int j = wave * 16 + col;

  __shared__ __align__(16) ushort_t Ah[2][16][AS];
  for (int i = tid; i < 2 * 16 * AS; i += 512) (&Ah[0][0][0])[i] = 0;

  short8 wf[4][KT];
#pragma unroll
  for (int nt = 0; nt < 4; ++nt) {
    int n = nt * 128 + j;
#pragma unroll
    for (int kt = 0; kt < KX; ++kt) {
      const float* p = Wih + n * KIN + kt * 32 + quad * 8;
      short8 w;
#pragma unroll
      for (int e = 0; e < 8; ++e) w[e] = (short)f2bf(p[e]);
      wf[nt][kt] = w;
    }
#pragma unroll
    for (int kt = 0; kt < 4; ++kt) {
      const float* p = Whh + n * 128 + kt * 32 + quad * 8;
      short8 w;
#pragma unroll
      for (int e = 0; e < 8; ++e) w[e] = (short)f2bf(p[e]);
      wf[nt][KX + kt] = w;
    }
  }
  const float bi  = bih[j]       + bhh[j];
  const float bf_ = bih[128 + j] + bhh[128 + j];
  const float bgi = bih[256 + j] + bhh[256 + j];
  const float bo  = bih[384 + j] + bhh[384 + j];

  floatx4 c = {0.f, 0.f, 0.f, 0.f};
  const int srow = tid / (KIN / 4), scol = (tid % (KIN / 4)) * 4;
  floatx4 xv = {0.f, 0.f, 0.f, 0.f};
  auto stage_load = [&](int t) {
    if (tid < NSTG && t < T_STEPS)
      xv = *(const floatx4*)(xin + (size_t)(t * BATCH + bg * 16 + srow) * KIN + scol);
  };
  auto stage_store = [&](int t, ushort_t (*buf)[AS]) {
    if (tid < NSTG && t < T_STEPS) {
#pragma unroll
      for (int e = 0; e < 4; ++e) buf[srow][scol + e] = f2bf(xv[e]);
    }
  };
  __syncthreads();
  stage_load(0); stage_store(0, Ah[0]); stage_load(1);
  __syncthreads();

  for (int t = 0; t < T_STEPS; ++t) {
    ushort_t (*rd)[AS] = Ah[t & 1];
    ushort_t (*wr)[AS] = Ah[(t & 1) ^ 1];
    short8 af[KT];
#pragma unroll
    for (int kt = 0; kt < KT; ++kt)
      af[kt] = *(const short8*)(&rd[col][kt * 32 + quad * 8]);
    floatx4 a0 = {0, 0, 0, 0}, a1 = {0, 0, 0, 0}, a2 = {0, 0, 0, 0},
            a3 = {0, 0, 0, 0};
#pragma unroll
    for (int kt = 0; kt < KT; ++kt) {
      short8 a = af[kt];
      a0 = __builtin_amdgcn_mfma_f32_16x16x32_bf16(a, wf[0][kt], a0, 0, 0, 0);
      a1 = __builtin_amdgcn_mfma_f32_16x16x32_bf16(a, wf[1][kt], a1, 0, 0, 0);
      a2 = __builtin_amdgcn_mfma_f32_16x16x32_bf16(a, wf[2][kt], a2, 0, 0, 0);
      a3 = __builtin_amdgcn_mfma_f32_16x16x32_bf16(a, wf[3][kt], a3, 0, 0, 0);
    }
    stage_store(t + 1, wr);
    stage_load(t + 2);
    size_t obase = (size_t)(t * BATCH + bg * 16) * HID + j;
#pragma unroll
    for (int r = 0; r < 4; ++r) {
      int row = quad * 4 + r;
      float iv = sigm(a0[r] + bi);
      float fv = sigm(a1[r] + bf_);
      float gv = tanh_(a2[r] + bgi);
      float ov = sigm(a3[r] + bo);
      float cn = __builtin_fmaf(fv, c[r], iv * gv);
      c[r] = cn;
      float hv = ov * tanh_(cn);
      wr[row][KIN + j] = f2bf(hv);
      hout[obase + (size_t)row * HID] = hv;
    }
    __syncthreads();
  }
}

extern "C" void kernel_launch(void* const* d_in, const int* in_sizes, int n_in,
                              void* d_out, int out_size, void* d_ws,
                              size_t ws_size, hipStream_t stream) {
  const float* x    = (const float*)d_in[0];  // [512,256,64]
  const float* Wih0 = (const float*)d_in[1];  // [512,64]
  const float* WihR = (const float*)d_in[2];  // [4,512,128]
  const float* Whh  = (const float*)d_in[3];  // [5,512,128]
  const float* bih  = (const float*)d_in[4];  // [5,512]
  const float* bhh  = (const float*)d_in[5];  // [5,512]
  float* out = (float*)d_out;                 // [512,256,128]

  if (ws_size >= WS_NEED) {
    int* flags = (int*)d_ws;
    uint_t* ring = (uint_t*)((char*)d_ws + 8192);
    init_flags<<<(NL * NBG * FLAG_STRIDE + 255) / 256, 256, 0, stream>>>(flags);
    lstm_pipe<<<NL * NBG, 512, 0, stream>>>(x, Wih0, WihR, Whh, bih, bhh,
                                            out, ring, flags);
    // R12 diagnostics (run after the real kernel; clobber only ws scratch)
    abl_body<true, 768><<<80, 512, 0, stream>>>(WihR, Whh, bih, bhh, ring,
                                                flags);
    abl_body<false, 1280><<<80, 512, 0, stream>>>(WihR, Whh, bih, bhh, ring,
                                                  flags);
  } else {
    lstm_layer<64><<<16, 512, 0, stream>>>(x, out, Wih0, Whh, bih, bhh);
    for (int l = 1; l < 5; ++l)
      lstm_layer<128><<<16, 512, 0, stream>>>(
          out, out, WihR + (size_t)(l - 1) * 512 * 128,
          Whh + (size_t)l * 512 * 128, bih + l * 512, bhh + l * 512);
  }
}

// Round 8
// 863.052 us; speedup vs baseline: 3.3386x; 3.3386x over previous
//
#include <hip/hip_runtime.h>

// 5-layer stacked LSTM, T=512 B=256 IN=64 H=128. Storage fp32; internal bf16
// MFMA with fp32 accum (R3 verified, absmax 4.9e-4).
//
// R13: de-serialize the BODY (R12 ablation: uncoupled body = 2990cy vs pipe
// 3260cy -> coupling is 8%; gates = 990cy; gateless floor 1997cy >> pipe-busy
// sums -> phase-serialized by the dependency chain). Restructure:
//  - pre-accumulator ping-pong pA/pB (bias + x.W_ih), 16 f32 each. Body t:
//    h-MFMAs accumulate ONTO pc (x part computed in body t-1); gates read pc;
//    pn = bias-init + x-MFMAs from Xr slot t+1 runs dependency-free and fills
//    the MFMA/LDS pipes under the gate VALU phase. Critical path = barrier ->
//    h-af read -> 4-deep h-MFMA chain -> gates -> h-write.
//  - bias folded into accumulator init (drops 16 v_adds/lane).
//  - slot window: body t reads x-slot t+1; commit at head (t+1-4..)&~3 is >=3
//    barriers earlier; pos (t+1)&7 next overwritten at head >= t+4. Safe.
// Sync machinery BIT-IDENTICAL to R10/R11 (verified): grouped 4-body
// fetch/commit, head-only vmcnt drains, LDS flag mirrors, 8-deep LDS x-ring,
// contiguous 4KB ring tiles, relaxed agent atomics, lgkm-only body barriers,
// 96KB LDS occupancy fence. R12 ablation kernels removed.
// Fallback: R3 layer-sequential path if ws too small.

typedef unsigned short ushort_t;
typedef unsigned int uint_t;
typedef unsigned long long ull_t;
typedef __attribute__((ext_vector_type(8))) short short8;
typedef __attribute__((ext_vector_type(4))) float floatx4;
typedef __attribute__((ext_vector_type(2))) float floatx2;

#define T_STEPS 512
#define BATCH   256
#define HID     128
#define NL      5
#define NBG     16
#define RING_R  64
#define PRIME   24
#define FLAG_STRIDE 16
#define SLOT_U  (BATCH * HID / 2)                  // uints per ring slot
#define RING_U  ((size_t)RING_R * SLOT_U)          // uints per layer ring
#define WS_NEED (8192 + 4 * RING_U * 4)
#define LDS_BYTES 98304   // 96KB occupancy fence (carve uses ~43.5KB)

__device__ __forceinline__ ushort_t f2bf(float f) {
  unsigned int u = __float_as_uint(f);
  u += 0x7FFF + ((u >> 16) & 1);  // RNE; values here are finite
  return (ushort_t)(u >> 16);
}
__device__ __forceinline__ float sigm(float x) {
  float e = __builtin_amdgcn_exp2f(-1.442695041f * x);
  return __builtin_amdgcn_rcpf(1.0f + e);
}
__device__ __forceinline__ float tanh_(float x) {
  float e = __builtin_amdgcn_exp2f(-2.885390082f * x);
  float s = __builtin_amdgcn_rcpf(1.0f + e);
  return __builtin_fmaf(2.0f, s, -1.0f);
}
__device__ __forceinline__ int flag_ld(const int* p) {
  return __hip_atomic_load(p, __ATOMIC_RELAXED, __HIP_MEMORY_SCOPE_AGENT);
}
__device__ __forceinline__ ull_t ring_ld8(const uint_t* base, int tid) {
  return __hip_atomic_load((const ull_t*)base + tid, __ATOMIC_RELAXED,
                           __HIP_MEMORY_SCOPE_AGENT);
}
__device__ __forceinline__ void ring_st8(uint_t* base, int tid, ull_t v) {
  __hip_atomic_store((ull_t*)base + tid, v, __ATOMIC_RELAXED,
                     __HIP_MEMORY_SCOPE_AGENT);
}

__global__ void init_flags(int* flags) {
  int i = blockIdx.x * 256 + threadIdx.x;
  if (i < NL * NBG * FLAG_STRIDE)
    __hip_atomic_store(&flags[i], 0, __ATOMIC_RELAXED,
                       __HIP_MEMORY_SCOPE_AGENT);
}

// ---------------------------------------------------------------- pipeline --
// Flag semantics: my_flag = N <=> ring slots 0..N-1 stored AND drained to L3.
// Published at head t (t%4==0, t>=4) after vmcnt(0)+s_barrier -> N = t-1.
// Consumer fetch of slot s requires flag >= s+1. Ring reuse: upstream
// overwrites slot s only when s - down_flag <= RING_R-16.
template <int KIN, bool SRC_F32, bool RING_OUT>
__device__ __forceinline__ void lstm_stage(
    unsigned char* lds,
    const float* xf32,              // layer-0 input (fp32) if SRC_F32
    const uint_t* ring_in,          // upstream ring (bf16 tiles)
    const float* __restrict__ Wih, const float* __restrict__ Whh,
    const float* __restrict__ bih, const float* __restrict__ bhh,
    uint_t* ring_out,               // this layer's ring (RING_OUT)
    float* out_f32,                 // d_out (last layer only)
    int* up_flag, int* down_flag, int* my_flag, int bg)
{
  constexpr int KX = KIN / 32, KT = KX + 4;
  constexpr int XS = KIN + 8;      // padded x row (ushorts)
  constexpr int HS = 128 + 8;

  typedef ushort_t (*XT)[16][XS];
  typedef ushort_t (*HT)[16][HS];
  XT Xr = (XT)lds;                                         // [8][16][XS]
  HT Hr = (HT)(lds + (size_t)8 * 16 * XS * 2);             // [2][16][HS]
  int* upm = (int*)(lds + (size_t)8 * 16 * XS * 2 + (size_t)2 * 16 * HS * 2);
  int* dnm = upm + 4;

  const int tid  = threadIdx.x;
  const int wave = tid >> 6;
  const int lane = tid & 63;
  const int col  = lane & 15;        // MFMA: A row / D col
  const int quad = lane >> 4;        // MFMA: k-group / D row-group
  const int j    = wave * 16 + col;  // gate/h column owned by this lane
  const int frow = tid >> 5;         // staging row (16)
  const int fc   = tid & 31;         // staging col group (32)

  for (int i = tid; i < 2 * 16 * HS; i += 512) (&Hr[0][0][0])[i] = 0;
  if (tid == 0) {
#pragma unroll
    for (int i = 0; i < 4; ++i) { upm[i] = 0; dnm[i] = 0; }  // under-report ok
  }

  // Wcat^T fragments, fp32 -> bf16 once, VGPR/AGPR-resident all 512 steps.
  short8 wf[4][KT];
#pragma unroll
  for (int nt = 0; nt < 4; ++nt) {
    int n = nt * 128 + j;
#pragma unroll
    for (int kt = 0; kt < KX; ++kt) {
      const float* p = Wih + n * KIN + kt * 32 + quad * 8;
      short8 w;
#pragma unroll
      for (int e = 0; e < 8; ++e) w[e] = (short)f2bf(p[e]);
      wf[nt][kt] = w;
    }
#pragma unroll
    for (int kt = 0; kt < 4; ++kt) {
      const float* p = Whh + n * 128 + kt * 32 + quad * 8;
      short8 w;
#pragma unroll
      for (int e = 0; e < 8; ++e) w[e] = (short)f2bf(p[e]);
      wf[nt][KX + kt] = w;
    }
  }
  const float bi  = bih[j]       + bhh[j];
  const float bf_ = bih[128 + j] + bhh[128 + j];
  const float bgi = bih[256 + j] + bhh[256 + j];
  const float bo  = bih[384 + j] + bhh[384 + j];

  floatx4 c = {0.f, 0.f, 0.f, 0.f};
  int pu = 0, pd = 0;           // tid0 pending flag loads
  ull_t  pf4[4];                // in-flight group fetch (ring path)
  floatx2 px4[4];               // in-flight group fetch (layer-0 path)
  floatx4 pA[4], pB[4];         // pre-accum ping-pong: bias + x.W (4 blocks)

  __syncthreads();  // zero-init + mirror init visible

  // ---------------- prologue: lag priming + commit slots 0..7 -------------
  if constexpr (!SRC_F32) {
    int v = 0;
    while ((v = flag_ld(up_flag)) < PRIME) __builtin_amdgcn_s_sleep(1);
    asm volatile("" ::: "memory");
    if (tid == 0) {
#pragma unroll
      for (int i = 0; i < 4; ++i) upm[i] = v;
      pu = v;
    }
    ull_t pr[8];
#pragma unroll
    for (int s = 0; s < 8; ++s)
      pr[s] = ring_ld8(ring_in + (size_t)s * SLOT_U + bg * 1024, tid);
#pragma unroll
    for (int s = 0; s < 8; ++s)
      *(ull_t*)(&Xr[s][frow][fc * 4]) = pr[s];
  } else {
    floatx2 pr[8];
#pragma unroll
    for (int s = 0; s < 8; ++s)
      pr[s] = *(const floatx2*)(xf32 +
                                ((size_t)s * BATCH + bg * 16 + frow) * 64 +
                                fc * 2);
#pragma unroll
    for (int s = 0; s < 8; ++s)
      *(uint_t*)(&Xr[s][frow][fc * 2]) =
          (uint_t)f2bf(pr[s][0]) | ((uint_t)f2bf(pr[s][1]) << 16);
  }
  // NO pre-issue here (R9 bug): head 0 issues slots 8..11.
  asm volatile("s_waitcnt lgkmcnt(0)\n\ts_barrier" ::: "memory");

  // pre for step 0 into pA: bias + x_0 . W_ih
  pA[0] = (floatx4){bi, bi, bi, bi};
  pA[1] = (floatx4){bf_, bf_, bf_, bf_};
  pA[2] = (floatx4){bgi, bgi, bgi, bgi};
  pA[3] = (floatx4){bo, bo, bo, bo};
#pragma unroll
  for (int kt = 0; kt < KX; ++kt) {
    short8 ax = *(const short8*)(&Xr[0][col][kt * 32 + quad * 8]);
    pA[0] = __builtin_amdgcn_mfma_f32_16x16x32_bf16(ax, wf[0][kt], pA[0], 0, 0, 0);
    pA[1] = __builtin_amdgcn_mfma_f32_16x16x32_bf16(ax, wf[1][kt], pA[1], 0, 0, 0);
    pA[2] = __builtin_amdgcn_mfma_f32_16x16x32_bf16(ax, wf[2][kt], pA[2], 0, 0, 0);
    pA[3] = __builtin_amdgcn_mfma_f32_16x16x32_bf16(ax, wf[3][kt], pA[3], 0, 0, 0);
  }

  auto body = [&](int t, floatx4 (&pc)[4], floatx4 (&pn)[4]) {
    if ((t & 3) == 0) {
      if (t >= 4) {
        // ---- head drain: publishes AND lands the 4 prefetch loads ----
        asm volatile("s_waitcnt vmcnt(0)\n\ts_barrier" ::: "memory");
        if (tid == 0)
          __hip_atomic_store(my_flag, t - 1, __ATOMIC_RELAXED,
                             __HIP_MEMORY_SCOPE_AGENT);
        // ---- commit slots t+4..t+7 (pos half disjoint from reads) ----
#pragma unroll
        for (int g = 0; g < 4; ++g) {
          const int s = t + 4 + g;
          if (s < T_STEPS) {
            if constexpr (SRC_F32)
              *(uint_t*)(&Xr[s & 7][frow][fc * 2]) =
                  (uint_t)f2bf(px4[g][0]) | ((uint_t)f2bf(px4[g][1]) << 16);
            else
              *(ull_t*)(&Xr[s & 7][frow][fc * 4]) = pf4[g];
          }
        }
      }
      // ---- issue fetch of slots t+8..t+11 (commit at head t+4) ----
      if (t + 8 < T_STEPS) {
        if constexpr (!SRC_F32) {
          int need = t + 12;
          if (need > T_STEPS) need = T_STEPS;
          if (upm[t & 3] < need) {               // steady state: never
            while (flag_ld(up_flag) < need) __builtin_amdgcn_s_sleep(1);
          }
        }
        asm volatile("" ::: "memory");  // no load hoisting above the gate
#pragma unroll
        for (int g = 0; g < 4; ++g) {
          const int s = t + 8 + g;
          if (s < T_STEPS) {
            if constexpr (SRC_F32)
              px4[g] = *(const floatx2*)(
                  xf32 + ((size_t)s * BATCH + bg * 16 + frow) * 64 + fc * 2);
            else
              pf4[g] = ring_ld8(
                  ring_in + (size_t)(s & (RING_R - 1)) * SLOT_U + bg * 1024,
                  tid);
          }
        }
      }
    }
    const int dn = dnm[t & 3];   // broadcast LDS read (written body t-2)

    // ---- export h_{t-1} (contiguous 4KB tile, fire-and-forget) ----
    if constexpr (RING_OUT) {
      if (t >= 1) {
        const int s = t - 1;
        if (s - dn > RING_R - 16) {                    // rare: direct spin
          while (s - flag_ld(down_flag) > RING_R - 16)
            __builtin_amdgcn_s_sleep(1);
          asm volatile("" ::: "memory");
        }
        ull_t h8 = *(const ull_t*)(&Hr[t & 1][frow][fc * 4]);
        ring_st8(ring_out + (size_t)(s & (RING_R - 1)) * SLOT_U + bg * 1024,
                 tid, h8);
      }
    }

    // ---- h-recurrence MFMAs accumulate onto pc (critical path) ----
#pragma unroll
    for (int kt = 0; kt < 4; ++kt) {
      short8 a = *(const short8*)(&Hr[t & 1][col][kt * 32 + quad * 8]);
      pc[0] = __builtin_amdgcn_mfma_f32_16x16x32_bf16(a, wf[0][KX + kt], pc[0], 0, 0, 0);
      pc[1] = __builtin_amdgcn_mfma_f32_16x16x32_bf16(a, wf[1][KX + kt], pc[1], 0, 0, 0);
      pc[2] = __builtin_amdgcn_mfma_f32_16x16x32_bf16(a, wf[2][KX + kt], pc[2], 0, 0, 0);
      pc[3] = __builtin_amdgcn_mfma_f32_16x16x32_bf16(a, wf[3][KX + kt], pc[3], 0, 0, 0);
    }

    // ---- OFF-PATH: pre(t+1) = bias + x_{t+1}.W_ih (fills pipes under gates)
    if (t + 1 < T_STEPS) {
      pn[0] = (floatx4){bi, bi, bi, bi};
      pn[1] = (floatx4){bf_, bf_, bf_, bf_};
      pn[2] = (floatx4){bgi, bgi, bgi, bgi};
      pn[3] = (floatx4){bo, bo, bo, bo};
#pragma unroll
      for (int kt = 0; kt < KX; ++kt) {
        short8 ax = *(const short8*)(&Xr[(t + 1) & 7][col][kt * 32 + quad * 8]);
        pn[0] = __builtin_amdgcn_mfma_f32_16x16x32_bf16(ax, wf[0][kt], pn[0], 0, 0, 0);
        pn[1] = __builtin_amdgcn_mfma_f32_16x16x32_bf16(ax, wf[1][kt], pn[1], 0, 0, 0);
        pn[2] = __builtin_amdgcn_mfma_f32_16x16x32_bf16(ax, wf[2][kt], pn[2], 0, 0, 0);
        pn[3] = __builtin_amdgcn_mfma_f32_16x16x32_bf16(ax, wf[3][kt], pn[3], 0, 0, 0);
      }
    }

    // ---- tid0 flag-mirror maintenance (commit old, issue new) ----
    if (tid == 0) {
      if constexpr (!SRC_F32) {
        upm[(t + 2) & 3] = pu;
        pu = flag_ld(up_flag);
      }
      if constexpr (RING_OUT) {
        dnm[(t + 2) & 3] = pd;
        pd = flag_ld(down_flag);
      }
    }

    // ---- cell update (lane-local; bias already inside pc) ----
    ushort_t (*wr)[HS] = Hr[(t & 1) ^ 1];
#pragma unroll
    for (int r = 0; r < 4; ++r) {
      float iv = sigm(pc[0][r]);
      float fv = sigm(pc[1][r]);
      float gv = tanh_(pc[2][r]);
      float ov = sigm(pc[3][r]);
      float cn = __builtin_fmaf(fv, c[r], iv * gv);
      c[r] = cn;
      float hv = ov * tanh_(cn);
      wr[quad * 4 + r][j] = f2bf(hv);  // own recurrence (+ export next body)
      if constexpr (!RING_OUT) {
        out_f32[((size_t)t * BATCH + bg * 16 + quad * 4 + r) * HID + j] = hv;
      }
    }

    // LDS-only barrier: orders buffers; agent stores stay in flight
    asm volatile("s_waitcnt lgkmcnt(0)\n\ts_barrier" ::: "memory");
  };

  for (int t = 0; t < T_STEPS; t += 2) {
    body(t, pA, pB);
    body(t + 1, pB, pA);
  }

  // ---- epilogue: export h_{T-1}, drain, final publish ----
  if constexpr (RING_OUT) {
    const int s = T_STEPS - 1;
    while (s - flag_ld(down_flag) > RING_R - 16) __builtin_amdgcn_s_sleep(1);
    asm volatile("" ::: "memory");
    ull_t h8 = *(const ull_t*)(&Hr[T_STEPS & 1][frow][fc * 4]);
    ring_st8(ring_out + (size_t)(s & (RING_R - 1)) * SLOT_U + bg * 1024, tid,
             h8);
  }
  asm volatile("s_waitcnt vmcnt(0)\n\ts_barrier" ::: "memory");
  if (tid == 0)
    __hip_atomic_store(my_flag, T_STEPS, __ATOMIC_RELAXED,
                       __HIP_MEMORY_SCOPE_AGENT);
}

__global__ __launch_bounds__(512) void lstm_pipe(
    const float* x, const float* Wih0, const float* WihR,
    const float* Whh, const float* bih, const float* bhh,
    float* out, uint_t* ring, int* flags)
{
  __shared__ __align__(16) unsigned char lds_raw[LDS_BYTES];
  const int l  = blockIdx.x >> 4;   // blockIdx = l*16+bg -> bg%8 XCD affinity
  const int bg = blockIdx.x & 15;
  int* mine = flags + (l * NBG + bg) * FLAG_STRIDE;
  int* up   = (l > 0) ? flags + ((l - 1) * NBG + bg) * FLAG_STRIDE : nullptr;
  int* down = (l < 4) ? flags + ((l + 1) * NBG + bg) * FLAG_STRIDE : nullptr;

  if (l == 0) {
    lstm_stage<64, true, true>(lds_raw, x, nullptr, Wih0, Whh, bih, bhh,
                               ring, nullptr, up, down, mine, bg);
  } else if (l < 4) {
    lstm_stage<128, false, true>(lds_raw, nullptr,
                                 ring + (size_t)(l - 1) * RING_U,
                                 WihR + (size_t)(l - 1) * 512 * 128,
                                 Whh + (size_t)l * 512 * 128,
                                 bih + l * 512, bhh + l * 512,
                                 ring + (size_t)l * RING_U, nullptr,
                                 up, down, mine, bg);
  } else {
    lstm_stage<128, false, false>(lds_raw, nullptr,
                                  ring + (size_t)3 * RING_U,
                                  WihR + (size_t)3 * 512 * 128,
                                  Whh + (size_t)4 * 512 * 128,
                                  bih + 4 * 512, bhh + 4 * 512,
                                  nullptr, out, up, nullptr, mine, bg);
  }
}

// ------------------------------------------------- fallback (R3, verified) --
template <int KIN>
__global__ __launch_bounds__(512) void lstm_layer(
    const float* xin, float* hout,
    const float* __restrict__ Wih, const float* __restrict__ Whh,
    const float* __restrict__ bih, const float* __restrict__ bhh)
{
  constexpr int KX = KIN / 32, KT = KX + 4;
  constexpr int AW = KIN + 128, AS = AW + 8;
  constexpr int NSTG = 16 * KIN / 4;

  const int bg = blockIdx.x, tid = threadIdx.x;
  const int wave = tid >> 6, lane = tid & 63;
  const int col = lane & 15, quad = lane >> 4;
  const int j = wave * 16 + col;

  __shared__ __align__(16) ushort_t Ah[2][16][AS];
  for (int i = tid; i < 2 * 16 * AS; i += 512) (&Ah[0][0][0])[i] = 0;

  short8 wf[4][KT];
#pragma unroll
  for (int nt = 0; nt < 4; ++nt) {
    int n = nt * 128 + j;
#pragma unroll
    for (int kt = 0; kt < KX; ++kt) {
      const float* p = Wih + n * KIN + kt * 32 + quad * 8;
      short8 w;
#pragma unroll
      for (int e = 0; e < 8; ++e) w[e] = (short)f2bf(p[e]);
      wf[nt][kt] = w;
    }
#pragma unroll
    for (int kt = 0; kt < 4; ++kt) {
      const float* p = Whh + n * 128 + kt * 32 + quad * 8;
      short8 w;
#pragma unroll
      for (int e = 0; e < 8; ++e) w[e] = (short)f2bf(p[e]);
      wf[nt][KX + kt] = w;
    }
  }
  const float bi  = bih[j]       + bhh[j];
  const float bf_ = bih[128 + j] + bhh[128 + j];
  const float bgi = bih[256 + j] + bhh[256 + j];
  const float bo  = bih[384 + j] + bhh[384 + j];

  floatx4 c = {0.f, 0.f, 0.f, 0.f};
  const int srow = tid / (KIN / 4), scol = (tid % (KIN / 4)) * 4;
  floatx4 xv = {0.f, 0.f, 0.f, 0.f};
  auto stage_load = [&](int t) {
    if (tid < NSTG && t < T_STEPS)
      xv = *(const floatx4*)(xin + (size_t)(t * BATCH + bg * 16 + srow) * KIN + scol);
  };
  auto stage_store = [&](int t, ushort_t (*buf)[AS]) {
    if (tid < NSTG && t < T_STEPS) {
#pragma unroll
      for (int e = 0; e < 4; ++e) buf[srow][scol + e] = f2bf(xv[e]);
    }
  };
  __syncthreads();
  stage_load(0); stage_store(0, Ah[0]); stage_load(1);
  __syncthreads();

  for (int t = 0; t < T_STEPS; ++t) {
    ushort_t (*rd)[AS] = Ah[t & 1];
    ushort_t (*wr)[AS] = Ah[(t & 1) ^ 1];
    short8 af[KT];
#pragma unroll
    for (int kt = 0; kt < KT; ++kt)
      af[kt] = *(const short8*)(&rd[col][kt * 32 + quad * 8]);
    floatx4 a0 = {0, 0, 0, 0}, a1 = {0, 0, 0, 0}, a2 = {0, 0, 0, 0},
            a3 = {0, 0, 0, 0};
#pragma unroll
    for (int kt = 0; kt < KT; ++kt) {
      short8 a = af[kt];
      a0 = __builtin_amdgcn_mfma_f32_16x16x32_bf16(a, wf[0][kt], a0, 0, 0, 0);
      a1 = __builtin_amdgcn_mfma_f32_16x16x32_bf16(a, wf[1][kt], a1, 0, 0, 0);
      a2 = __builtin_amdgcn_mfma_f32_16x16x32_bf16(a, wf[2][kt], a2, 0, 0, 0);
      a3 = __builtin_amdgcn_mfma_f32_16x16x32_bf16(a, wf[3][kt], a3, 0, 0, 0);
    }
    stage_store(t + 1, wr);
    stage_load(t + 2);
    size_t obase = (size_t)(t * BATCH + bg * 16) * HID + j;
#pragma unroll
    for (int r = 0; r < 4; ++r) {
      int row = quad * 4 + r;
      float iv = sigm(a0[r] + bi);
      float fv = sigm(a1[r] + bf_);
      float gv = tanh_(a2[r] + bgi);
      float ov = sigm(a3[r] + bo);
      float cn = __builtin_fmaf(fv, c[r], iv * gv);
      c[r] = cn;
      float hv = ov * tanh_(cn);
      wr[row][KIN + j] = f2bf(hv);
      hout[obase + (size_t)row * HID] = hv;
    }
    __syncthreads();
  }
}

extern "C" void kernel_launch(void* const* d_in, const int* in_sizes, int n_in,
                              void* d_out, int out_size, void* d_ws,
                              size_t ws_size, hipStream_t stream) {
  const float* x    = (const float*)d_in[0];  // [512,256,64]
  const float* Wih0 = (const float*)d_in[1];  // [512,64]
  const float* WihR = (const float*)d_in[2];  // [4,512,128]
  const float* Whh  = (const float*)d_in[3];  // [5,512,128]
  const float* bih  = (const float*)d_in[4];  // [5,512]
  const float* bhh  = (const float*)d_in[5];  // [5,512]
  float* out = (float*)d_out;                 // [512,256,128]

  if (ws_size >= WS_NEED) {
    int* flags = (int*)d_ws;
    uint_t* ring = (uint_t*)((char*)d_ws + 8192);
    init_flags<<<(NL * NBG * FLAG_STRIDE + 255) / 256, 256, 0, stream>>>(flags);
    lstm_pipe<<<NL * NBG, 512, 0, stream>>>(x, Wih0, WihR, Whh, bih, bhh,
                                            out, ring, flags);
  } else {
    lstm_layer<64><<<16, 512, 0, stream>>>(x, out, Wih0, Whh, bih, bhh);
    for (int l = 1; l < 5; ++l)
      lstm_layer<128><<<16, 512, 0, stream>>>(
          out, out, WihR + (size_t)(l - 1) * 512 * 128,
          Whh + (size_t)l * 512 * 128, bih + l * 512, bhh + l * 512);
  }
}